// Round 3
// baseline (5308.937 us; speedup 1.0000x reference)
//
#include <hip/hip_runtime.h>
#include <cstdint>

#define B_SZ   2048
#define T_SZ   80
#define VOCABN 80
#define EMBN   8
#define HID    256
#define G4     1024
#define TILE   16
#define NBLK   (B_SZ / TILE)   // 128
#define NWAVE  8
#define NTHR   (NWAVE * 64)    // 512
#define NCHUNK 24              // 8 (W1h) + 16 (W2) per step
#define CHELEM 32768           // bf16 elems per 64KB chunk

typedef __bf16 bf16;
typedef __attribute__((ext_vector_type(8))) __bf16 bf16x8;
typedef __attribute__((ext_vector_type(4))) float  f32x4;

__device__ __forceinline__ float sigf(float x)   { return 1.0f / (1.0f + __expf(-x)); }
__device__ __forceinline__ float tanhf2(float x) { return 1.0f - 2.0f / (__expf(2.0f * x) + 1.0f); }

__device__ __forceinline__ unsigned short f2bf(float f) {
    union { float f; unsigned int u; } v; v.f = f;
    unsigned int u = v.u;
    return (unsigned short)((u + 0x7FFFu + ((u >> 16) & 1u)) >> 16);
}

// Swizzled h-tile addressing: row-major [16][256] bf16, 512B rows, 16B blocks
// rotated by 2*row within the row (proven correct in R1).
__device__ __forceinline__ int hswz(int row, int col) {
    return row * 256 + ((((col >> 3) + 2 * row) & 31) << 3) + (col & 7);
}

// A-fragment read (inverse of hswz), proven in R1.
#define AFRAG(hptr, k_) (*(const bf16x8*)&(hptr)[lc * 256 + (((4 * (k_) + lg + 2 * lc) & 31) << 3)])

// ---------------- prep kernels: k-major fragment packing ----------------
__global__ void prep_eg(const float* __restrict__ emb, const float* __restrict__ W1,
                        const float* __restrict__ b1, float* __restrict__ eg) {
    int idx = blockIdx.x * blockDim.x + threadIdx.x;
    if (idx >= VOCABN * G4) return;
    int v = idx >> 10, n = idx & 1023;
    float s = b1[n];
#pragma unroll
    for (int e = 0; e < EMBN; ++e) s += emb[v * EMBN + e] * W1[e * G4 + n];
    eg[idx] = s;
}

// w1p: [k(8)][nt(64)][lane(64)][8]  (k-slice = one 64KB chunk)
__global__ void prep_w1(const float* __restrict__ W1, unsigned short* __restrict__ w1p) {
    int idx = blockIdx.x * blockDim.x + threadIdx.x;
    if (idx >= 8 * 64 * 64) return;
    int lane = idx & 63, nt = (idx >> 6) & 63, k = idx >> 12;
    int scol = (nt << 4) + (lane & 15);
    int r0 = EMBN + k * 32 + ((lane >> 4) << 3);
#pragma unroll
    for (int e = 0; e < 8; ++e)
        w1p[idx * 8 + e] = f2bf(W1[(r0 + e) * G4 + scol]);
}

// w2p: [k(16)][nt(64)][lane(64)][8]; k 0..7 = h1(x) rows, 8..15 = h2 rows
__global__ void prep_w2(const float* __restrict__ W2, unsigned short* __restrict__ w2p) {
    int idx = blockIdx.x * blockDim.x + threadIdx.x;
    if (idx >= 16 * 64 * 64) return;
    int lane = idx & 63, nt = (idx >> 6) & 63, k = idx >> 12;
    int scol = (nt << 4) + (lane & 15);
    int r0 = k * 32 + ((lane >> 4) << 3);
#pragma unroll
    for (int e = 0; e < 8; ++e)
        w2p[idx * 8 + e] = f2bf(W2[(r0 + e) * G4 + scol]);
}

// ---------------- fused 2-layer LSTM + loss ----------------
// Stage one 64KB chunk: wave issues 8 global_load_lds_dwordx4; LDS dest is
// wave-uniform base (HW adds lane*16), global src is per-lane -> pure linear copy.
__device__ __forceinline__ void stage_chunk(const bf16* __restrict__ g, bf16* l,
                                            int wid, int lane) {
#pragma unroll
    for (int j = 0; j < 8; ++j) {
        const int f = j * 512 + wid * 64;
        __builtin_amdgcn_global_load_lds(
            (const __attribute__((address_space(1))) void*)(g + (size_t)(f + lane) * 8),
            (__attribute__((address_space(3))) void*)(l + (size_t)f * 8),
            16, 0, 0);
    }
}

#define CHUNK_MM(af) do {                                                       \
    const bf16* wb_ = wbuf[cflat & 1];                                          \
    _Pragma("unroll")                                                           \
    for (int g_ = 0; g_ < 4; ++g_)                                              \
        _Pragma("unroll")                                                       \
        for (int d_ = 0; d_ < 2; ++d_) {                                        \
            const int nt_ = g_ * 16 + 2 * wid + d_;                             \
            bf16x8 w_ = *(const bf16x8*)&wb_[(nt_ * 64 + lane) * 8];            \
            acc[g_][d_] = __builtin_amdgcn_mfma_f32_16x16x32_bf16(af, w_, acc[g_][d_], 0, 0, 0); \
        }                                                                       \
} while (0)

#define GATHER_EG(tt) do {                                                      \
    _Pragma("unroll")                                                           \
    for (int r_ = 0; r_ < 4; ++r_) {                                            \
        const int row_ = lg * 4 + r_;                                           \
        const int tok_ = toks[row_][tt];                                        \
        const float* e_ = eg + tok_ * G4 + wid * 32 + lc;                       \
        _Pragma("unroll")                                                       \
        for (int d_ = 0; d_ < 2; ++d_) {                                        \
            egv[0][d_][r_] = e_[d_ * 16 + 0];                                   \
            egv[1][d_][r_] = e_[d_ * 16 + 256];                                 \
            egv[2][d_][r_] = e_[d_ * 16 + 512];                                 \
            egv[3][d_][r_] = e_[d_ * 16 + 768];                                 \
        }                                                                       \
    }                                                                           \
} while (0)

__global__ __launch_bounds__(NTHR, 2)
void lstm_fused(const int* __restrict__ feat, const int* __restrict__ labels,
                const float* __restrict__ eg,
                const bf16* __restrict__ w1k,
                const bf16* __restrict__ w2k,
                const float* __restrict__ b2,
                const float* __restrict__ Wd, const float* __restrict__ bd,
                float* __restrict__ out)
{
    __shared__ __align__(16) bf16 wbuf[2][CHELEM];        // 128 KB
    __shared__ __align__(16) bf16 h1s[TILE * 256];        // 8 KB
    __shared__ __align__(16) bf16 h2s[TILE * 256];        // 8 KB
    __shared__ int   toks[TILE][T_SZ];                    // 5 KB
    __shared__ float logitb[TILE][VOCABN + 4];
    __shared__ float lossb[TILE];

    const int tid  = threadIdx.x;
    const int lane = tid & 63;
    const int wid  = tid >> 6;
    const int lc   = lane & 15;
    const int lg   = lane >> 4;
    const int b0   = blockIdx.x * TILE;

    for (int i = tid; i < TILE * 256; i += NTHR) {
        h1s[i] = (bf16)0.0f;
        h2s[i] = (bf16)0.0f;
    }
    for (int i = tid; i < TILE * T_SZ; i += NTHR) {
        int r = i / T_SZ, t = i - r * T_SZ;
        toks[r][t] = feat[(b0 + r) * T_SZ + t];
    }
    __syncthreads();   // toks/h visible before gather + first step

    const f32x4 zf = {0.f, 0.f, 0.f, 0.f};
    f32x4 c1[2], c2[2];
    c1[0] = zf; c1[1] = zf; c2[0] = zf; c2[1] = zf;

    float b2r[4][2];
#pragma unroll
    for (int g = 0; g < 4; ++g)
#pragma unroll
        for (int d = 0; d < 2; ++d)
            b2r[g][d] = b2[g * 256 + wid * 32 + d * 16 + lc];

    float egv[4][2][4];
    f32x4 acc[4][2];

    // prologue: chunk 0 in flight, eg for t=0 gathered
    stage_chunk(w1k, wbuf[0], wid, lane);
    GATHER_EG(0);
    int cflat = 0;

    for (int t = 0; t < T_SZ; ++t) {
        // =================== layer 1: chunks 0..7 ===================
#pragma unroll
        for (int g = 0; g < 4; ++g) { acc[g][0] = zf; acc[g][1] = zf; }
        bf16x8 a1[8];
        for (int kc = 0; kc < 8; ++kc) {
            __syncthreads();   // implicit vmcnt(0): chunk cflat resident + all waves synced
            {
                const int nf = cflat + 1;
                if (nf < NCHUNK * T_SZ) {
                    const int c = nf % NCHUNK;
                    const bf16* cb = (c < 8) ? (w1k + (size_t)c * CHELEM)
                                             : (w2k + (size_t)(c - 8) * CHELEM);
                    stage_chunk(cb, wbuf[nf & 1], wid, lane);
                }
            }
            if (kc == 0) {
#pragma unroll
                for (int k = 0; k < 8; ++k) a1[k] = AFRAG(h1s, k);
            }
            CHUNK_MM(a1[kc]);
            ++cflat;
        }
        // L1 pointwise: gates + state update, write h1_t (single buffer; safe
        // because every wave preloaded a1 at kc==0 behind barriers).
#pragma unroll
        for (int d2 = 0; d2 < 2; ++d2) {
            const int hcol = wid * 32 + d2 * 16 + lc;
#pragma unroll
            for (int r = 0; r < 4; ++r) {
                const int row = lg * 4 + r;
                float gi = acc[0][d2][r] + egv[0][d2][r];
                float gj = acc[1][d2][r] + egv[1][d2][r];
                float gf = acc[2][d2][r] + egv[2][d2][r];
                float go = acc[3][d2][r] + egv[3][d2][r];
                float cn = c1[d2][r] * sigf(gf + 1.0f) + sigf(gi) * tanhf2(gj);
                float h  = tanhf2(cn) * sigf(go);
                c1[d2][r] = cn;
                h1s[hswz(row, hcol)] = (bf16)h;
            }
        }

        // =================== layer 2: chunks 8..23 ===================
#pragma unroll
        for (int g = 0; g < 4; ++g) { acc[g][0] = zf; acc[g][1] = zf; }
        bf16x8 a2h[8];
        for (int kc = 0; kc < 16; ++kc) {
            __syncthreads();
            {
                const int nf = cflat + 1;
                if (nf < NCHUNK * T_SZ) {
                    const int c = nf % NCHUNK;
                    const bf16* cb = (c < 8) ? (w1k + (size_t)c * CHELEM)
                                             : (w2k + (size_t)(c - 8) * CHELEM);
                    stage_chunk(cb, wbuf[nf & 1], wid, lane);
                }
            }
            if (kc == 8) {
#pragma unroll
                for (int k = 0; k < 8; ++k) a2h[k] = AFRAG(h2s, k);
                if (t + 1 < T_SZ) GATHER_EG(t + 1);   // one chunk of latency cover
            }
            if (kc < 8) {
                bf16x8 af = AFRAG(h1s, kc);           // x-part: fresh h1_t (stable)
                CHUNK_MM(af);
            } else {
                CHUNK_MM(a2h[kc - 8]);                // h-part: h2_{t-1} from regs
            }
            ++cflat;
        }
        // L2 pointwise: write h2_t (safe via a2h preload behind barriers)
#pragma unroll
        for (int d2 = 0; d2 < 2; ++d2) {
            const int hcol = wid * 32 + d2 * 16 + lc;
#pragma unroll
            for (int r = 0; r < 4; ++r) {
                const int row = lg * 4 + r;
                float gi = acc[0][d2][r] + b2r[0][d2];
                float gj = acc[1][d2][r] + b2r[1][d2];
                float gf = acc[2][d2][r] + b2r[2][d2];
                float go = acc[3][d2][r] + b2r[3][d2];
                float cn = c2[d2][r] * sigf(gf + 1.0f) + sigf(gi) * tanhf2(gj);
                float h  = tanhf2(cn) * sigf(go);
                c2[d2][r] = cn;
                h2s[hswz(row, hcol)] = (bf16)h;
            }
        }
    }
    __syncthreads();

    // ---- epilogue: logits = h2_last @ Wd + bd, log-softmax NLL, mean ----
    for (int pp = tid; pp < TILE * VOCABN; pp += NTHR) {
        int row = pp / VOCABN, v = pp - row * VOCABN;
        float s = bd[v];
        for (int k = 0; k < HID; ++k)
            s += (float)h2s[hswz(row, k)] * Wd[k * VOCABN + v];
        logitb[row][v] = s;
    }
    __syncthreads();
    if (tid < TILE) {
        const int row = tid;
        float m = -1e30f;
        for (int v = 0; v < VOCABN; ++v) m = fmaxf(m, logitb[row][v]);
        float s = 0.f;
        for (int v = 0; v < VOCABN; ++v) s += __expf(logitb[row][v] - m);
        int lab = labels[b0 + row];
        lossb[row] = m + __logf(s) - logitb[row][lab];
    }
    __syncthreads();
    if (tid == 0) {
        float s = 0.f;
#pragma unroll
        for (int r = 0; r < TILE; ++r) s += lossb[r];
        atomicAdd(out, s * (1.0f / (float)B_SZ));
    }
}

extern "C" void kernel_launch(void* const* d_in, const int* in_sizes, int n_in,
                              void* d_out, int out_size, void* d_ws, size_t ws_size,
                              hipStream_t stream)
{
    (void)in_sizes; (void)n_in; (void)out_size; (void)ws_size;
    const int*   feat   = (const int*)d_in[0];
    const int*   labels = (const int*)d_in[1];
    const float* emb    = (const float*)d_in[2];
    const float* W1     = (const float*)d_in[3];
    const float* b1     = (const float*)d_in[4];
    const float* W2     = (const float*)d_in[5];
    const float* b2     = (const float*)d_in[6];
    const float* Wd     = (const float*)d_in[7];
    const float* bd     = (const float*)d_in[8];
    float* out = (float*)d_out;

    char* ws = (char*)d_ws;
    float* eg  = (float*)ws;                          // 327680 B
    bf16*  w1k = (bf16*)(ws + 327680);                // 524288 B
    bf16*  w2k = (bf16*)(ws + 327680 + 524288);       // 1048576 B

    hipMemsetAsync(d_out, 0, sizeof(float), stream);
    prep_eg<<<(VOCABN * G4 + 255) / 256, 256, 0, stream>>>(emb, W1, b1, eg);
    prep_w1<<<(8 * 64 * 64) / 256, 256, 0, stream>>>(W1, (unsigned short*)w1k);
    prep_w2<<<(16 * 64 * 64) / 256, 256, 0, stream>>>(W2, (unsigned short*)w2k);
    lstm_fused<<<NBLK, NTHR, 0, stream>>>(feat, labels, eg, w1k, w2k, b2, Wd, bd, out);
}